// Round 13
// baseline (101.057 us; speedup 1.0000x reference)
//
#include <hip/hip_runtime.h>

#define VOCAB 16384
#define N_Q   16384   // B*h*w = 16*32*32
#define C     32
#define HW    1024    // h*w
#define VCH   16
#define CODES_PER_CH 1024
#define TILES_PER_CH 64
#define GRP    8          // tiles per staging group
#define NGRP   8          // groups per chunk
#define GBYTES 18432      // [8KB hi | 8KB lo | 2KB enq] contiguous blob

typedef _Float16 half8 __attribute__((ext_vector_type(8)));
typedef float f32x4  __attribute__((ext_vector_type(4)));

// ---- fused prep: E -> contiguous 18KB group blobs (f16 hi/lo frags + enq quads),
//      + conv wpack + keys/counts init ----
// frag layout (HW-verified r6-r11): within tile, lane=(ko<<4)|(j&15), elem 0..7
__global__ __launch_bounds__(256) void k_prepE(const float* __restrict__ emb,
                                               char* __restrict__ Eblob,
                                               const float* __restrict__ convw,
                                               float* __restrict__ wp,
                                               unsigned long long* __restrict__ keys,
                                               int* __restrict__ counts) {
    int bx = blockIdx.x;
    if (bx >= 64) {
        if (bx == 64) {          // conv-weight repack to [tap][cin][cout]
            for (int k = threadIdx.x; k < C * C * 9; k += 256) {
                int cout = k / (C * 9);
                int r = k % (C * 9);
                int cin = r / 9;
                int tap = r % 9;
                wp[(tap * C + cin) * C + cout] = convw[k];
            }
        } else if (bx == 65) {
            for (int k = threadIdx.x; k < VOCAB; k += 256) keys[k] = ~0ULL;
        } else {
            for (int k = threadIdx.x; k < VOCAB; k += 256) counts[k] = 0;
        }
        return;
    }
    int j = bx * 256 + threadIdx.x;   // code row
    const float4* e4 = reinterpret_cast<const float4*>(emb + j * C);
    float s = 0.f;
    float v[C];
#pragma unroll
    for (int k = 0; k < 8; ++k) {
        float4 t = e4[k];
        v[4 * k] = t.x; v[4 * k + 1] = t.y; v[4 * k + 2] = t.z; v[4 * k + 3] = t.w;
        s += t.x * t.x + t.y * t.y + t.z * t.z + t.w * t.w;
    }
    float en2 = 0.5f * s;
    int tg = j >> 4, G = tg >> 3, tt = tg & 7;
    char* gb = Eblob + (size_t)G * GBYTES;
    *reinterpret_cast<float4*>(gb + 16384 + tt * 256 + (j & 15) * 16)
        = make_float4(en2, en2, en2, en2);
#pragma unroll
    for (int ko = 0; ko < 4; ++ko) {
        half8 vh, vl;
#pragma unroll
        for (int e = 0; e < 8; ++e) {
            float x = v[ko * 8 + e];
            _Float16 h = (_Float16)x;
            vh[e] = h;
            vl[e] = (_Float16)(x - (float)h);
        }
        int lane = (ko << 4) | (j & 15);
        *reinterpret_cast<half8*>(gb + tt * 1024 + lane * 16) = vh;
        *reinterpret_cast<half8*>(gb + 8192 + tt * 1024 + lane * 16) = vl;
    }
}

// ---- staging: one 18KB contiguous blob -> LDS via global_load_lds(16B), branch-free ----
__device__ __forceinline__ void stage_grp(const char* gb, char* db, int w, int lane) {
#pragma unroll
    for (int k = 0; k < 5; ++k) {
        int widx = w + 4 * k;     // 18 wave-copies of 1KB over 4 waves
        if (widx < 18) {
            __builtin_amdgcn_global_load_lds(
                (const __attribute__((address_space(1))) void*)(gb + widx * 1024 + lane * 16),
                (__attribute__((address_space(3))) void*)(db + widx * 1024 + lane * 16),
                16, 0, 0);
        }
    }
}

// ---- MFMA argmin: packed running-min (and_or + min3, compiler-fused) ----
// d' = ||e||^2/2 - q.e ; f16 3-way split; block = 4 waves x 64 queries; grid (64,16)
__global__ __launch_bounds__(256, 3) void k_argmin(
    const float* __restrict__ f,
    const char* __restrict__ Eblob,
    unsigned long long* __restrict__ keys) {
    __shared__ __align__(16) char lds[2 * GBYTES];
    int tid = threadIdx.x;
    int lane = tid & 63;
    int w = tid >> 6;
    int wid = blockIdx.x * 4 + w;        // 0..255, 64 queries each
    int chunk = blockIdx.y;

    // Q prologue: load 64 queries from f (NCHW), negate, f16 hi/lo split
    half8 a_hi[4], a_lo[4];
    int c0 = (lane >> 4) * 8;
#pragma unroll
    for (int qq = 0; qq < 4; ++qq) {
        int n = (wid * 4 + qq) * 16 + (lane & 15);
        int b = n >> 10, rem = n & 1023;
        const float* fp = f + (b * C + c0) * HW + rem;
#pragma unroll
        for (int e = 0; e < 8; ++e) {
            float x = -fp[e * HW];            // negated
            _Float16 h = (_Float16)x;
            a_hi[qq][e] = h;
            a_lo[qq][e] = (_Float16)(x - (float)h);
        }
    }

    float best[4][4];
#pragma unroll
    for (int qq = 0; qq < 4; ++qq)
#pragma unroll
        for (int r = 0; r < 4; ++r) best[qq][r] = __uint_as_float(0x7F800000u);  // +inf

    const char* gb0 = Eblob + (size_t)(chunk * NGRP) * GBYTES;

    stage_grp(gb0, lds, w, lane);
    __syncthreads();   // group 0 resident

    unsigned mpack = 0xFFFFFFC0u;
    // keep mask in a register so (x & m) | t fuses to v_and_or_b32 (t stays SGPR)
    asm("" : "+v"(mpack));

    for (int g = 0; g < NGRP; ++g) {
        if (g + 1 < NGRP)
            stage_grp(gb0 + (size_t)(g + 1) * GBYTES, lds + ((g + 1) & 1) * GBYTES, w, lane);
        const char* bbl = lds + (g & 1) * GBYTES + lane * 16;                 // hi/lo per-lane base
        const char* ebl = lds + (g & 1) * GBYTES + 16384 + (lane & 15) * 16;  // enq base
        unsigned tbase = (unsigned)(g * GRP);
#pragma unroll
        for (int tp = 0; tp < GRP / 2; ++tp) {   // tile pairs
            int tt0 = 2 * tp, tt1 = 2 * tp + 1;
            half8 bh0 = *(const half8*)(bbl + tt0 * 1024);
            half8 bl0 = *(const half8*)(bbl + 8192 + tt0 * 1024);
            f32x4 eq0 = *(const f32x4*)(ebl + tt0 * 256);
            half8 bh1 = *(const half8*)(bbl + tt1 * 1024);
            half8 bl1 = *(const half8*)(bbl + 8192 + tt1 * 1024);
            f32x4 eq1 = *(const f32x4*)(ebl + tt1 * 256);
            unsigned t0 = tbase + (unsigned)tt0;
            unsigned t1 = tbase + (unsigned)tt1;
#pragma unroll
            for (int qq = 0; qq < 4; ++qq) {
                f32x4 acc0 = __builtin_amdgcn_mfma_f32_16x16x32_f16(a_hi[qq], bh0, eq0, 0, 0, 0);
                acc0 = __builtin_amdgcn_mfma_f32_16x16x32_f16(a_hi[qq], bl0, acc0, 0, 0, 0);
                acc0 = __builtin_amdgcn_mfma_f32_16x16x32_f16(a_lo[qq], bh0, acc0, 0, 0, 0);
                f32x4 acc1 = __builtin_amdgcn_mfma_f32_16x16x32_f16(a_hi[qq], bh1, eq1, 0, 0, 0);
                acc1 = __builtin_amdgcn_mfma_f32_16x16x32_f16(a_hi[qq], bl1, acc1, 0, 0, 0);
                acc1 = __builtin_amdgcn_mfma_f32_16x16x32_f16(a_lo[qq], bh1, acc1, 0, 0, 0);
#pragma unroll
                for (int r = 0; r < 4; ++r) {
                    unsigned p0 = (__float_as_uint(acc0[r]) & mpack) | t0;  // v_and_or_b32
                    unsigned p1 = (__float_as_uint(acc1[r]) & mpack) | t1;
                    best[qq][r] = fminf(best[qq][r],
                                        fminf(__uint_as_float(p0), __uint_as_float(p1)));  // v_min3_f32
                }
            }
        }
        __syncthreads();   // all waves done with buf[g&1]; next stage drained
    }

    // 16-lane column reduce per query row, then one atomicMin per query
#pragma unroll
    for (int qq = 0; qq < 4; ++qq)
#pragma unroll
        for (int r = 0; r < 4; ++r) {
            float d = best[qq][r];
            int t = (int)(__float_as_uint(d) & 63u);
            int code = chunk * CODES_PER_CH + (t << 4) + (lane & 15);
#pragma unroll
            for (int m = 1; m < 16; m <<= 1) {
                float od = __shfl_xor(d, m, 64);
                int oc = __shfl_xor(code, m, 64);
                if (od < d || (od == d && oc < code)) { d = od; code = oc; }
            }
            if ((lane & 15) == 0) {
                int row = ((lane >> 4) * 4) + r;
                int n = (wid * 4 + qq) * 16 + row;
                unsigned bits = __float_as_uint(d);
                unsigned s = ((int)bits >= 0) ? (bits | 0x80000000u) : ~bits;
                unsigned long long key = ((unsigned long long)s << 32) | (unsigned)code;
                atomicMin(&keys[n], key);
            }
        }
}

// ---- conv3x3 residual + fhat + loss partials + bincount (keys-direct gather) ----
__global__ __launch_bounds__(256) void k_conv(const unsigned long long* __restrict__ keys,
                                              const float* __restrict__ emb,
                                              const float* __restrict__ wp,
                                              const float* __restrict__ bias,
                                              const float* __restrict__ f,
                                              int* __restrict__ counts,
                                              float* __restrict__ out,
                                              float* __restrict__ lpart) {
    __shared__ float sZ[128 * 33];
    __shared__ float sW[9216];      // full [tap][cin][cout] weight block
    __shared__ float red[256];
    int blk = blockIdx.x;
    int b = blk >> 4;
    int r0 = (blk & 15) * 2;
    int tid = threadIdx.x;

    {   // stage weights: 2304 float4
        float4* dW = reinterpret_cast<float4*>(sW);
        const float4* sWp = reinterpret_cast<const float4*>(wp);
        for (int i = tid; i < 2304; i += 256) dW[i] = sWp[i];
    }
    {   // stage 4 rows (r0-1..r0+2)
        int px = tid >> 1, half = tid & 1;
        int row = px >> 5, col = px & 31;
        int gy = r0 - 1 + row;
        float* d = &sZ[px * 33 + half * 16];
        if (gy >= 0 && gy < 32) {
            int id = (int)(keys[b * HW + gy * 32 + col] & 0xFFFFFFFFULL);
            const float4* s = reinterpret_cast<const float4*>(emb + id * C + half * 16);
#pragma unroll
            for (int k = 0; k < 4; ++k) {
                float4 v = s[k];
                d[4 * k] = v.x; d[4 * k + 1] = v.y; d[4 * k + 2] = v.z; d[4 * k + 3] = v.w;
            }
        } else {
#pragma unroll
            for (int k = 0; k < 16; ++k) d[k] = 0.f;
        }
    }
    __syncthreads();

    int tx = tid & 31, ty = (tid >> 5) & 1, cg = tid >> 6;
    int co0 = cg * 8;
    int gy = r0 + ty;
    if (cg == 0) {
        int id = (int)(keys[b * HW + gy * 32 + tx] & 0xFFFFFFFFULL);
        atomicAdd(&counts[id], 1);
    }
    float acc[8];
#pragma unroll
    for (int u = 0; u < 8; ++u) acc[u] = bias[co0 + u];
    for (int dy = -1; dy <= 1; ++dy) {
        for (int dx = -1; dx <= 1; ++dx) {
            int gx = tx + dx;
            if (gx < 0 || gx >= 32) continue;
            const float* zp = &sZ[((ty + 1 + dy) * 32 + gx) * 33];
            int tap = (dy + 1) * 3 + (dx + 1);
            const float* wtap = &sW[tap * C * C + co0];
#pragma unroll
            for (int cin = 0; cin < C; ++cin) {
                float z = zp[cin];
                const f32x4* w4 = reinterpret_cast<const f32x4*>(wtap + cin * C);
                f32x4 wa = w4[0], wb = w4[1];
#pragma unroll
                for (int u = 0; u < 4; ++u) acc[u] = fmaf(z, wa[u], acc[u]);
#pragma unroll
                for (int u = 0; u < 4; ++u) acc[4 + u] = fmaf(z, wb[u], acc[4 + u]);
            }
        }
    }
    float lsum = 0.f;
#pragma unroll
    for (int u = 0; u < 8; ++u) {
        int cc = co0 + u;
        float zqv = sZ[((ty + 1) * 32 + tx) * 33 + cc];
        float fh = 0.5f * (zqv + acc[u]);   // h*(1-r) + (conv+b)*r, r=0.5
        int off = (b * C + cc) * HW + gy * 32 + tx;
        out[off] = fh;
        float diff = fh - f[off];
        lsum += diff * diff;
    }
    red[tid] = lsum;
    __syncthreads();
    for (int s = 128; s > 0; s >>= 1) {
        if (tid < s) red[tid] += red[tid + s];
        __syncthreads();
    }
    if (tid == 0) lpart[blk] = red[0];
}

// ---- scalars ----
__global__ __launch_bounds__(256) void k_final(const float* __restrict__ lpart,
                                               const int* __restrict__ counts,
                                               float* __restrict__ out) {
    __shared__ float red[256];
    __shared__ int redi[256];
    int tid = threadIdx.x;
    int used = 0;
    for (int i = tid; i < VOCAB; i += 256) used += (counts[i] != 0) ? 1 : 0;
    red[tid] = lpart[tid];
    redi[tid] = used;
    __syncthreads();
    for (int s = 128; s > 0; s >>= 1) {
        if (tid < s) { red[tid] += red[tid + s]; redi[tid] += redi[tid + s]; }
        __syncthreads();
    }
    if (tid == 0) {
        out[N_Q * C]     = 1.25f * red[0] / (float)(N_Q * C);      // (1+BETA)*MSE
        out[N_Q * C + 1] = 100.f * (float)redi[0] / (float)VOCAB;  // counts>=1
    }
}

extern "C" void kernel_launch(void* const* d_in, const int* in_sizes, int n_in,
                              void* d_out, int out_size, void* d_ws, size_t ws_size,
                              hipStream_t stream) {
    const float* f     = (const float*)d_in[0];
    const float* emb   = (const float*)d_in[1];
    const float* convw = (const float*)d_in[2];
    const float* convb = (const float*)d_in[3];
    float* out = (float*)d_out;
    float* ws  = (float*)d_ws;

    // float-unit offsets (total ~2.6 MB)
    float*  wp     = ws;                              // 9216
    float*  lpart  = ws + 9216;                       // 256
    int*    counts = (int*)(ws + 9472);               // 16384
    unsigned long long* keys = (unsigned long long*)(ws + 25856);  // 16384 u64
    char*   Eblob  = (char*)(ws + 58624);             // 128 groups x 18KB = 2.304 MB

    k_prepE<<<67, 256, 0, stream>>>(emb, Eblob, convw, wp, keys, counts);
    dim3 g2(64, VCH);
    k_argmin<<<g2, 256, 0, stream>>>(f, Eblob, keys);
    k_conv<<<256, 256, 0, stream>>>(keys, emb, wp, convb, f, counts, out, lpart);
    k_final<<<1, 256, 0, stream>>>(lpart, counts, out);
}

// Round 14
// 89.928 us; speedup vs baseline: 1.1238x; 1.1238x over previous
//
#include <hip/hip_runtime.h>

#define VOCAB 16384
#define N_Q   16384   // B*h*w = 16*32*32
#define C     32
#define HW    1024    // h*w
#define VCH   16
#define CODES_PER_CH 1024
#define TILES_PER_CH 64
#define GRP    8          // tiles per staging group
#define NGRP   8          // groups per chunk
#define GBYTES 18432      // [8KB hi | 8KB lo | 2KB enq] contiguous blob

typedef _Float16 half8 __attribute__((ext_vector_type(8)));
typedef float f32x4  __attribute__((ext_vector_type(4)));

// ---- fused prep: E -> contiguous 18KB group blobs (f16 hi/lo frags + enq quads),
//      + conv wpack + keys/counts init ----
// frag layout (HW-verified r6-r13): within tile, lane=(ko<<4)|(j&15), elem 0..7
__global__ __launch_bounds__(256) void k_prepE(const float* __restrict__ emb,
                                               char* __restrict__ Eblob,
                                               const float* __restrict__ convw,
                                               float* __restrict__ wp,
                                               unsigned long long* __restrict__ keys,
                                               int* __restrict__ counts) {
    int bx = blockIdx.x;
    if (bx >= 64) {
        if (bx == 64) {          // conv-weight repack to [tap][cin][cout]
            for (int k = threadIdx.x; k < C * C * 9; k += 256) {
                int cout = k / (C * 9);
                int r = k % (C * 9);
                int cin = r / 9;
                int tap = r % 9;
                wp[(tap * C + cin) * C + cout] = convw[k];
            }
        } else if (bx == 65) {
            for (int k = threadIdx.x; k < VOCAB; k += 256) keys[k] = ~0ULL;
        } else {
            for (int k = threadIdx.x; k < VOCAB; k += 256) counts[k] = 0;
        }
        return;
    }
    int j = bx * 256 + threadIdx.x;   // code row
    const float4* e4 = reinterpret_cast<const float4*>(emb + j * C);
    float s = 0.f;
    float v[C];
#pragma unroll
    for (int k = 0; k < 8; ++k) {
        float4 t = e4[k];
        v[4 * k] = t.x; v[4 * k + 1] = t.y; v[4 * k + 2] = t.z; v[4 * k + 3] = t.w;
        s += t.x * t.x + t.y * t.y + t.z * t.z + t.w * t.w;
    }
    float en2 = 0.5f * s;
    int tg = j >> 4, G = tg >> 3, tt = tg & 7;
    char* gb = Eblob + (size_t)G * GBYTES;
    *reinterpret_cast<float4*>(gb + 16384 + tt * 256 + (j & 15) * 16)
        = make_float4(en2, en2, en2, en2);
#pragma unroll
    for (int ko = 0; ko < 4; ++ko) {
        half8 vh, vl;
#pragma unroll
        for (int e = 0; e < 8; ++e) {
            float x = v[ko * 8 + e];
            _Float16 h = (_Float16)x;
            vh[e] = h;
            vl[e] = (_Float16)(x - (float)h);
        }
        int lane = (ko << 4) | (j & 15);
        *reinterpret_cast<half8*>(gb + tt * 1024 + lane * 16) = vh;
        *reinterpret_cast<half8*>(gb + 8192 + tt * 1024 + lane * 16) = vl;
    }
}

// ---- staging: one 18KB contiguous blob -> LDS via global_load_lds(16B), branch-free ----
__device__ __forceinline__ void stage_grp(const char* gb, char* db, int w, int lane) {
#pragma unroll
    for (int k = 0; k < 5; ++k) {
        int widx = w + 4 * k;     // 18 wave-copies of 1KB over 4 waves
        if (widx < 18) {
            __builtin_amdgcn_global_load_lds(
                (const __attribute__((address_space(1))) void*)(gb + widx * 1024 + lane * 16),
                (__attribute__((address_space(3))) void*)(db + widx * 1024 + lane * 16),
                16, 0, 0);
        }
    }
}

// ---- MFMA argmin: packed running-min (and_or + min, compiler-fused) ----
// d' = ||e||^2/2 - q.e ; f16 3-way split; block = 4 waves x 64 queries; grid (64,16)
// launch_bounds(256,2): 256-reg unified budget so the ~100-reg live set stays in
// arch VGPRs (r7-r13 evidence: arch cap = budget/2; smaller budgets forced AGPR
// round-trips on every tile). LDS still caps residency at 4 blocks/CU.
__global__ __launch_bounds__(256, 2) void k_argmin(
    const float* __restrict__ f,
    const char* __restrict__ Eblob,
    unsigned long long* __restrict__ keys) {
    __shared__ __align__(16) char lds[2 * GBYTES];
    int tid = threadIdx.x;
    int lane = tid & 63;
    int w = tid >> 6;
    int wid = blockIdx.x * 4 + w;        // 0..255, 64 queries each
    int chunk = blockIdx.y;

    // Q prologue: load 64 queries from f (NCHW), negate, f16 hi/lo split
    half8 a_hi[4], a_lo[4];
    int c0 = (lane >> 4) * 8;
#pragma unroll
    for (int qq = 0; qq < 4; ++qq) {
        int n = (wid * 4 + qq) * 16 + (lane & 15);
        int b = n >> 10, rem = n & 1023;
        const float* fp = f + (b * C + c0) * HW + rem;
#pragma unroll
        for (int e = 0; e < 8; ++e) {
            float x = -fp[e * HW];            // negated
            _Float16 h = (_Float16)x;
            a_hi[qq][e] = h;
            a_lo[qq][e] = (_Float16)(x - (float)h);
        }
    }

    float best[4][4];
#pragma unroll
    for (int qq = 0; qq < 4; ++qq)
#pragma unroll
        for (int r = 0; r < 4; ++r) best[qq][r] = __uint_as_float(0x7F800000u);  // +inf

    const char* gb0 = Eblob + (size_t)(chunk * NGRP) * GBYTES;

    stage_grp(gb0, lds, w, lane);
    __syncthreads();   // group 0 resident

    unsigned mpack = 0xFFFFFFC0u;
    // keep mask in a register so (x & m) | t fuses to v_and_or_b32 (t stays SGPR)
    asm("" : "+v"(mpack));

    for (int g = 0; g < NGRP; ++g) {
        if (g + 1 < NGRP)
            stage_grp(gb0 + (size_t)(g + 1) * GBYTES, lds + ((g + 1) & 1) * GBYTES, w, lane);
        const char* bbl = lds + (g & 1) * GBYTES + lane * 16;                 // hi/lo per-lane base
        const char* ebl = lds + (g & 1) * GBYTES + 16384 + (lane & 15) * 16;  // enq base
        unsigned tbase = (unsigned)(g * GRP);
#pragma unroll
        for (int tt = 0; tt < GRP; ++tt) {
            half8 bh = *(const half8*)(bbl + tt * 1024);
            half8 bl = *(const half8*)(bbl + 8192 + tt * 1024);
            f32x4 eq = *(const f32x4*)(ebl + tt * 256);
            unsigned t = tbase + (unsigned)tt;
#pragma unroll
            for (int qq = 0; qq < 4; ++qq) {
                f32x4 acc = __builtin_amdgcn_mfma_f32_16x16x32_f16(a_hi[qq], bh, eq, 0, 0, 0);
                acc = __builtin_amdgcn_mfma_f32_16x16x32_f16(a_hi[qq], bl, acc, 0, 0, 0);
                acc = __builtin_amdgcn_mfma_f32_16x16x32_f16(a_lo[qq], bh, acc, 0, 0, 0);
#pragma unroll
                for (int r = 0; r < 4; ++r) {
                    unsigned p = (__float_as_uint(acc[r]) & mpack) | t;   // v_and_or_b32
                    best[qq][r] = fminf(best[qq][r], __uint_as_float(p)); // v_min_f32
                }
            }
        }
        __syncthreads();   // all waves done with buf[g&1]; next stage drained
    }

    // 16-lane column reduce per query row, then one atomicMin per query
#pragma unroll
    for (int qq = 0; qq < 4; ++qq)
#pragma unroll
        for (int r = 0; r < 4; ++r) {
            float d = best[qq][r];
            int t = (int)(__float_as_uint(d) & 63u);
            int code = chunk * CODES_PER_CH + (t << 4) + (lane & 15);
#pragma unroll
            for (int m = 1; m < 16; m <<= 1) {
                float od = __shfl_xor(d, m, 64);
                int oc = __shfl_xor(code, m, 64);
                if (od < d || (od == d && oc < code)) { d = od; code = oc; }
            }
            if ((lane & 15) == 0) {
                int row = ((lane >> 4) * 4) + r;
                int n = (wid * 4 + qq) * 16 + row;
                unsigned bits = __float_as_uint(d);
                unsigned s = ((int)bits >= 0) ? (bits | 0x80000000u) : ~bits;
                unsigned long long key = ((unsigned long long)s << 32) | (unsigned)code;
                atomicMin(&keys[n], key);
            }
        }
}

// ---- conv3x3 residual + fhat + loss partials + bincount (keys-direct gather) ----
__global__ __launch_bounds__(256) void k_conv(const unsigned long long* __restrict__ keys,
                                              const float* __restrict__ emb,
                                              const float* __restrict__ wp,
                                              const float* __restrict__ bias,
                                              const float* __restrict__ f,
                                              int* __restrict__ counts,
                                              float* __restrict__ out,
                                              float* __restrict__ lpart) {
    __shared__ float sZ[128 * 33];
    __shared__ float sW[9216];      // full [tap][cin][cout] weight block
    __shared__ float red[256];
    int blk = blockIdx.x;
    int b = blk >> 4;
    int r0 = (blk & 15) * 2;
    int tid = threadIdx.x;

    {   // stage weights: 2304 float4
        float4* dW = reinterpret_cast<float4*>(sW);
        const float4* sWp = reinterpret_cast<const float4*>(wp);
        for (int i = tid; i < 2304; i += 256) dW[i] = sWp[i];
    }
    {   // stage 4 rows (r0-1..r0+2)
        int px = tid >> 1, half = tid & 1;
        int row = px >> 5, col = px & 31;
        int gy = r0 - 1 + row;
        float* d = &sZ[px * 33 + half * 16];
        if (gy >= 0 && gy < 32) {
            int id = (int)(keys[b * HW + gy * 32 + col] & 0xFFFFFFFFULL);
            const float4* s = reinterpret_cast<const float4*>(emb + id * C + half * 16);
#pragma unroll
            for (int k = 0; k < 4; ++k) {
                float4 v = s[k];
                d[4 * k] = v.x; d[4 * k + 1] = v.y; d[4 * k + 2] = v.z; d[4 * k + 3] = v.w;
            }
        } else {
#pragma unroll
            for (int k = 0; k < 16; ++k) d[k] = 0.f;
        }
    }
    __syncthreads();

    int tx = tid & 31, ty = (tid >> 5) & 1, cg = tid >> 6;
    int co0 = cg * 8;
    int gy = r0 + ty;
    if (cg == 0) {
        int id = (int)(keys[b * HW + gy * 32 + tx] & 0xFFFFFFFFULL);
        atomicAdd(&counts[id], 1);
    }
    float acc[8];
#pragma unroll
    for (int u = 0; u < 8; ++u) acc[u] = bias[co0 + u];
    for (int dy = -1; dy <= 1; ++dy) {
        for (int dx = -1; dx <= 1; ++dx) {
            int gx = tx + dx;
            if (gx < 0 || gx >= 32) continue;
            const float* zp = &sZ[((ty + 1 + dy) * 32 + gx) * 33];
            int tap = (dy + 1) * 3 + (dx + 1);
            const float* wtap = &sW[tap * C * C + co0];
#pragma unroll
            for (int cin = 0; cin < C; ++cin) {
                float z = zp[cin];
                const f32x4* w4 = reinterpret_cast<const f32x4*>(wtap + cin * C);
                f32x4 wa = w4[0], wb = w4[1];
#pragma unroll
                for (int u = 0; u < 4; ++u) acc[u] = fmaf(z, wa[u], acc[u]);
#pragma unroll
                for (int u = 0; u < 4; ++u) acc[4 + u] = fmaf(z, wb[u], acc[4 + u]);
            }
        }
    }
    float lsum = 0.f;
#pragma unroll
    for (int u = 0; u < 8; ++u) {
        int cc = co0 + u;
        float zqv = sZ[((ty + 1) * 32 + tx) * 33 + cc];
        float fh = 0.5f * (zqv + acc[u]);   // h*(1-r) + (conv+b)*r, r=0.5
        int off = (b * C + cc) * HW + gy * 32 + tx;
        out[off] = fh;
        float diff = fh - f[off];
        lsum += diff * diff;
    }
    red[tid] = lsum;
    __syncthreads();
    for (int s = 128; s > 0; s >>= 1) {
        if (tid < s) red[tid] += red[tid + s];
        __syncthreads();
    }
    if (tid == 0) lpart[blk] = red[0];
}

// ---- scalars ----
__global__ __launch_bounds__(256) void k_final(const float* __restrict__ lpart,
                                               const int* __restrict__ counts,
                                               float* __restrict__ out) {
    __shared__ float red[256];
    __shared__ int redi[256];
    int tid = threadIdx.x;
    int used = 0;
    for (int i = tid; i < VOCAB; i += 256) used += (counts[i] != 0) ? 1 : 0;
    red[tid] = lpart[tid];
    redi[tid] = used;
    __syncthreads();
    for (int s = 128; s > 0; s >>= 1) {
        if (tid < s) { red[tid] += red[tid + s]; redi[tid] += redi[tid + s]; }
        __syncthreads();
    }
    if (tid == 0) {
        out[N_Q * C]     = 1.25f * red[0] / (float)(N_Q * C);      // (1+BETA)*MSE
        out[N_Q * C + 1] = 100.f * (float)redi[0] / (float)VOCAB;  // counts>=1
    }
}

extern "C" void kernel_launch(void* const* d_in, const int* in_sizes, int n_in,
                              void* d_out, int out_size, void* d_ws, size_t ws_size,
                              hipStream_t stream) {
    const float* f     = (const float*)d_in[0];
    const float* emb   = (const float*)d_in[1];
    const float* convw = (const float*)d_in[2];
    const float* convb = (const float*)d_in[3];
    float* out = (float*)d_out;
    float* ws  = (float*)d_ws;

    // float-unit offsets (total ~2.6 MB)
    float*  wp     = ws;                              // 9216
    float*  lpart  = ws + 9216;                       // 256
    int*    counts = (int*)(ws + 9472);               // 16384
    unsigned long long* keys = (unsigned long long*)(ws + 25856);  // 16384 u64
    char*   Eblob  = (char*)(ws + 58624);             // 128 groups x 18KB = 2.304 MB

    k_prepE<<<67, 256, 0, stream>>>(emb, Eblob, convw, wp, keys, counts);
    dim3 g2(64, VCH);
    k_argmin<<<g2, 256, 0, stream>>>(f, Eblob, keys);
    k_conv<<<256, 256, 0, stream>>>(keys, emb, wp, convb, f, counts, out, lpart);
    k_final<<<1, 256, 0, stream>>>(lpart, counts, out);
}